// Round 1
// baseline (167.649 us; speedup 1.0000x reference)
//
#include <hip/hip_runtime.h>
#include <math.h>

#define NU 96
#define IMG 32
#define SHAPE (NU * IMG)            // 3072
#define NUNITS (NU * NU)            // 9216
#define PLANE (SHAPE * SHAPE)       // 9437184
#define SHAPE4 (SHAPE / 4)          // 768 float4 per row
#define IMG4 (IMG / 4)              // 8 float4 per tile row

// ---------------------------------------------------------------------------
// Kernel 1: z[u,v] = sum_{i,j} (som[u*32+i, v*32+j] - x[i,j])^2 / var[...]
// One block per unit tile (96x96 blocks), 256 threads, one float4 per thread.
// ---------------------------------------------------------------------------
__global__ __launch_bounds__(256) void zkernel(const float* __restrict__ x,
                                               const float* __restrict__ som,
                                               const float* __restrict__ var,
                                               float* __restrict__ z) {
    const int v = blockIdx.x, u = blockIdx.y, t = threadIdx.x;
    const int i = t >> 3;        // tile row 0..31
    const int jv = t & 7;        // float4 col 0..7

    const float4* __restrict__ som4 = (const float4*)som;
    const float4* __restrict__ var4 = (const float4*)var;
    const float4* __restrict__ x4   = (const float4*)x;

    const int idx = (u * IMG + i) * SHAPE4 + v * IMG4 + jv;
    const float4 s  = som4[idx];
    const float4 w  = var4[idx];
    const float4 xx = x4[i * IMG4 + jv];

    const float d0 = s.x - xx.x, d1 = s.y - xx.y, d2 = s.z - xx.z, d3 = s.w - xx.w;
    float p = d0 * d0 / w.x + d1 * d1 / w.y + d2 * d2 / w.z + d3 * d3 / w.w;

    // wave64 shuffle reduction
    #pragma unroll
    for (int off = 32; off > 0; off >>= 1) p += __shfl_down(p, off, 64);

    __shared__ float lds[4];
    const int wave = t >> 6, lane = t & 63;
    if (lane == 0) lds[wave] = p;
    __syncthreads();
    if (t == 0) z[u * NU + v] = lds[0] + lds[1] + lds[2] + lds[3];
}

// ---------------------------------------------------------------------------
// Kernel 2: flat argmin over z[9216], first-occurrence tie-break (jnp.argmin).
// Single block of 256 threads.
// ---------------------------------------------------------------------------
__global__ __launch_bounds__(256) void argmin_kernel(const float* __restrict__ z,
                                                     int* __restrict__ bmu) {
    const int t = threadIdx.x;
    float mv = 3.402823466e38f;
    int mi = 0x7fffffff;
    for (int k = t; k < NUNITS; k += 256) {
        const float val = z[k];
        if (val < mv || (val == mv && k < mi)) { mv = val; mi = k; }
    }
    #pragma unroll
    for (int off = 32; off > 0; off >>= 1) {
        const float ov = __shfl_down(mv, off, 64);
        const int   oi = __shfl_down(mi, off, 64);
        if (ov < mv || (ov == mv && oi < mi)) { mv = ov; mi = oi; }
    }
    __shared__ float svals[4];
    __shared__ int   sidx[4];
    const int wave = t >> 6, lane = t & 63;
    if (lane == 0) { svals[wave] = mv; sidx[wave] = mi; }
    __syncthreads();
    if (t == 0) {
        #pragma unroll
        for (int w = 1; w < 4; w++) {
            if (svals[w] < mv || (svals[w] == mv && sidx[w] < mi)) { mv = svals[w]; mi = sidx[w]; }
        }
        bmu[0] = mi;
    }
}

// ---------------------------------------------------------------------------
// Kernel 3: per-element som/var update + radius/lr outputs.
// One block per unit tile; per-block scalars computed redundantly (cheap).
// ---------------------------------------------------------------------------
__global__ __launch_bounds__(256) void update_kernel(const float* __restrict__ x,
                                                     const float* __restrict__ som,
                                                     const float* __restrict__ var,
                                                     const float* __restrict__ radius,
                                                     const float* __restrict__ lrates,
                                                     const float* __restrict__ bmu_count,
                                                     const int* __restrict__ bmu,
                                                     float* __restrict__ out) {
    const int v = blockIdx.x, u = blockIdx.y, t = threadIdx.x;
    const int flat = bmu[0];
    const int bi = flat / NU, bj = flat % NU;

    const float r    = radius[flat];
    const float lr_b = lrates[flat];
    const float dm   = 1.0f / (2.0f * r * r);
    const float constant = -logf(1e-7f / lr_b) / dm;

    const float du = (float)u - (float)bi;
    const float dv = (float)v - (float)bj;
    const float cart = sqrtf(du * du + dv * dv);
    const float modifier = (cart > r) ? 0.0f : cart;
    const float fm = lrates[u * NU + v] * expf(-modifier) * dm;
    const float sg = 1.0f / (1.0f + expf(-(cart / constant)));
    float va = 0.4f + sg;                       // ALPHA - 0.5 = 0.4
    va = fminf(fmaxf(va, 0.0f), 1.0f);
    const float one_minus_va = 1.0f - va;

    const float4* __restrict__ som4 = (const float4*)som;
    const float4* __restrict__ var4 = (const float4*)var;
    const float4* __restrict__ x4   = (const float4*)x;
    float4* __restrict__ out_som = (float4*)out;
    float4* __restrict__ out_var = (float4*)(out + (size_t)PLANE);

    const int i = t >> 3, jv = t & 7;
    const int idx = (u * IMG + i) * SHAPE4 + v * IMG4 + jv;
    const float4 s  = som4[idx];
    const float4 w  = var4[idx];
    const float4 xx = x4[i * IMG4 + jv];

    float4 ns, nv;
    {
        float n = s.x + fm * (xx.x - s.x);
        float d = xx.x - n;
        nv.x = va * w.x + one_minus_va * d * d;
        ns.x = fminf(fmaxf(n, 0.0f), 1.0f);
    }
    {
        float n = s.y + fm * (xx.y - s.y);
        float d = xx.y - n;
        nv.y = va * w.y + one_minus_va * d * d;
        ns.y = fminf(fmaxf(n, 0.0f), 1.0f);
    }
    {
        float n = s.z + fm * (xx.z - s.z);
        float d = xx.z - n;
        nv.z = va * w.z + one_minus_va * d * d;
        ns.z = fminf(fmaxf(n, 0.0f), 1.0f);
    }
    {
        float n = s.w + fm * (xx.w - s.w);
        float d = xx.w - n;
        nv.w = va * w.w + one_minus_va * d * d;
        ns.w = fminf(fmaxf(n, 0.0f), 1.0f);
    }
    out_som[idx] = ns;
    out_var[idx] = nv;

    if (t == 0) {
        float* out_rad = out + 2 * (size_t)PLANE;
        float* out_lr  = out_rad + NUNITS;
        const int uv = u * NU + v;
        const float b0 = bmu_count[(size_t)flat * 10];
        const float rv = (uv == flat) ? expf(-b0 / 15.0f) : radius[uv];
        const float lv = (uv == flat) ? expf(-b0 / 25.0f) : lrates[uv];
        out_rad[uv] = fmaxf(rv, 1e-5f);
        out_lr[uv]  = fmaxf(lv, 1e-5f);
    }
}

extern "C" void kernel_launch(void* const* d_in, const int* in_sizes, int n_in,
                              void* d_out, int out_size, void* d_ws, size_t ws_size,
                              hipStream_t stream) {
    const float* x         = (const float*)d_in[0];
    const float* som       = (const float*)d_in[1];
    const float* var       = (const float*)d_in[2];
    const float* radius    = (const float*)d_in[3];
    const float* lrates    = (const float*)d_in[4];
    const float* bmu_count = (const float*)d_in[5];
    float* out = (float*)d_out;

    float* z  = (float*)d_ws;
    int* bmu  = (int*)((float*)d_ws + NUNITS);

    dim3 grid(NU, NU);
    zkernel<<<grid, 256, 0, stream>>>(x, som, var, z);
    argmin_kernel<<<1, 256, 0, stream>>>(z, bmu);
    update_kernel<<<grid, 256, 0, stream>>>(x, som, var, radius, lrates, bmu_count, bmu, out);
}

// Round 3
// 159.827 us; speedup vs baseline: 1.0489x; 1.0489x over previous
//
#include <hip/hip_runtime.h>
#include <math.h>

#define NU 96
#define IMG 32
#define SHAPE (NU * IMG)            // 3072
#define NUNITS (NU * NU)            // 9216
#define PLANE (SHAPE * SHAPE)       // 9437184
#define SHAPE4 (SHAPE / 4)          // 768 float4 per row
#define IMG4 (IMG / 4)              // 8 float4 per tile row
#define NSLOTS 64                   // argmin scatter slots (contention control)

typedef float vfloat4 __attribute__((ext_vector_type(4)));  // clang-native, NT-store OK

// ---------------------------------------------------------------------------
// Kernel 1: z[u,v] = sum_{i,j} (som - x)^2 / var over the 32x32 tile, then
// fused argmin via packed-key atomicMin into 64 slots.
// Key = (float_bits(z) << 32) | flat_index. z >= 0 so bits are monotonic;
// min over keys = min z with first-occurrence (smallest flat) tie-break.
// One block per unit tile (96x96 blocks), 256 threads, one float4 per thread.
// ---------------------------------------------------------------------------
__global__ __launch_bounds__(256) void zargmin_kernel(const float* __restrict__ x,
                                                      const float* __restrict__ som,
                                                      const float* __restrict__ var,
                                                      unsigned long long* __restrict__ slots) {
    const int v = blockIdx.x, u = blockIdx.y, t = threadIdx.x;
    const int i = t >> 3;        // tile row 0..31
    const int jv = t & 7;        // float4 col 0..7

    const vfloat4* __restrict__ som4 = (const vfloat4*)som;
    const vfloat4* __restrict__ var4 = (const vfloat4*)var;
    const vfloat4* __restrict__ x4   = (const vfloat4*)x;

    const int idx = (u * IMG + i) * SHAPE4 + v * IMG4 + jv;
    const vfloat4 s  = som4[idx];
    const vfloat4 w  = var4[idx];
    const vfloat4 xx = x4[i * IMG4 + jv];

    const vfloat4 d = s - xx;
    const vfloat4 q = d * d / w;
    float p = q.x + q.y + q.z + q.w;

    // wave64 shuffle reduction
    #pragma unroll
    for (int off = 32; off > 0; off >>= 1) p += __shfl_down(p, off, 64);

    __shared__ float lds[4];
    const int wave = t >> 6, lane = t & 63;
    if (lane == 0) lds[wave] = p;
    __syncthreads();
    if (t == 0) {
        const float z = lds[0] + lds[1] + lds[2] + lds[3];
        const unsigned int flat = (unsigned int)(u * NU + v);
        const unsigned long long key =
            ((unsigned long long)__float_as_uint(z) << 32) | (unsigned long long)flat;
        atomicMin(&slots[flat & (NSLOTS - 1)], key);
    }
}

// ---------------------------------------------------------------------------
// Kernel 2: per-element som/var update + radius/lr outputs.
// Every wave first min-reduces the 64 argmin slots (butterfly shuffle) to get
// the BMU; then one float4 of the update per thread. Streaming outputs use
// non-temporal stores.
// ---------------------------------------------------------------------------
__global__ __launch_bounds__(256) void update_kernel(const float* __restrict__ x,
                                                     const float* __restrict__ som,
                                                     const float* __restrict__ var,
                                                     const float* __restrict__ radius,
                                                     const float* __restrict__ lrates,
                                                     const float* __restrict__ bmu_count,
                                                     const unsigned long long* __restrict__ slots,
                                                     float* __restrict__ out) {
    const int v = blockIdx.x, u = blockIdx.y, t = threadIdx.x;

    // --- recover BMU from the 64 slots (each wave redundantly; all L2 hits) ---
    unsigned long long key = slots[t & 63];
    #pragma unroll
    for (int off = 32; off > 0; off >>= 1) {
        const unsigned long long o = __shfl_xor(key, off, 64);
        key = (o < key) ? o : key;
    }
    const int flat = (int)(key & 0xFFFFFFFFull);
    const int bi = flat / NU, bj = flat % NU;

    const float r    = radius[flat];
    const float lr_b = lrates[flat];
    const float dm   = 1.0f / (2.0f * r * r);
    const float constant = -logf(1e-7f / lr_b) / dm;

    const float du = (float)u - (float)bi;
    const float dv = (float)v - (float)bj;
    const float cart = sqrtf(du * du + dv * dv);
    const float modifier = (cart > r) ? 0.0f : cart;
    const float fm = lrates[u * NU + v] * expf(-modifier) * dm;
    const float sg = 1.0f / (1.0f + expf(-(cart / constant)));
    float va = 0.4f + sg;                       // ALPHA - 0.5 = 0.4
    va = fminf(fmaxf(va, 0.0f), 1.0f);
    const float one_minus_va = 1.0f - va;

    const vfloat4* __restrict__ som4 = (const vfloat4*)som;
    const vfloat4* __restrict__ var4 = (const vfloat4*)var;
    const vfloat4* __restrict__ x4   = (const vfloat4*)x;
    vfloat4* __restrict__ out_som = (vfloat4*)out;
    vfloat4* __restrict__ out_var = (vfloat4*)(out + (size_t)PLANE);

    const int i = t >> 3, jv = t & 7;
    const int idx = (u * IMG + i) * SHAPE4 + v * IMG4 + jv;
    const vfloat4 s  = som4[idx];
    const vfloat4 w  = var4[idx];
    const vfloat4 xx = x4[i * IMG4 + jv];

    const vfloat4 n = s + fm * (xx - s);        // unclipped new_som (used for var)
    const vfloat4 d = xx - n;
    const vfloat4 nv = va * w + one_minus_va * d * d;
    vfloat4 ns;
    ns.x = fminf(fmaxf(n.x, 0.0f), 1.0f);
    ns.y = fminf(fmaxf(n.y, 0.0f), 1.0f);
    ns.z = fminf(fmaxf(n.z, 0.0f), 1.0f);
    ns.w = fminf(fmaxf(n.w, 0.0f), 1.0f);

    __builtin_nontemporal_store(ns, &out_som[idx]);
    __builtin_nontemporal_store(nv, &out_var[idx]);

    if (t == 0) {
        float* out_rad = out + 2 * (size_t)PLANE;
        float* out_lr  = out_rad + NUNITS;
        const int uv = u * NU + v;
        const float b0 = bmu_count[(size_t)flat * 10];
        const float rv = (uv == flat) ? expf(-b0 / 15.0f) : radius[uv];
        const float lv = (uv == flat) ? expf(-b0 / 25.0f) : lrates[uv];
        out_rad[uv] = fmaxf(rv, 1e-5f);
        out_lr[uv]  = fmaxf(lv, 1e-5f);
    }
}

extern "C" void kernel_launch(void* const* d_in, const int* in_sizes, int n_in,
                              void* d_out, int out_size, void* d_ws, size_t ws_size,
                              hipStream_t stream) {
    const float* x         = (const float*)d_in[0];
    const float* som       = (const float*)d_in[1];
    const float* var       = (const float*)d_in[2];
    const float* radius    = (const float*)d_in[3];
    const float* lrates    = (const float*)d_in[4];
    const float* bmu_count = (const float*)d_in[5];
    float* out = (float*)d_out;

    unsigned long long* slots = (unsigned long long*)d_ws;

    // init argmin slots to all-ones (greater than any valid packed key)
    (void)hipMemsetAsync(slots, 0xFF, NSLOTS * sizeof(unsigned long long), stream);

    dim3 grid(NU, NU);
    zargmin_kernel<<<grid, 256, 0, stream>>>(x, som, var, slots);
    update_kernel<<<grid, 256, 0, stream>>>(x, som, var, radius, lrates, bmu_count, slots, out);
}